// Round 5
// baseline (205.280 us; speedup 1.0000x reference)
//
#include <hip/hip_runtime.h>
#include <stdint.h>

typedef unsigned short u16;
typedef __attribute__((ext_vector_type(8))) short short8;    // 8 bf16 = 4 VGPRs (MFMA A/B frag)
typedef __attribute__((ext_vector_type(4))) float float4v;   // MFMA C/D frag
typedef __attribute__((ext_vector_type(4))) u16 ushort4v;
typedef __attribute__((ext_vector_type(4))) unsigned int uint4v;
typedef __attribute__((ext_vector_type(2))) unsigned int uint2v;

#define MFMA_BF16(a, b, c) __builtin_amdgcn_mfma_f32_16x16x32_bf16((a), (b), (c), 0, 0, 0)

__device__ __forceinline__ u16 f2bf(float f) {   // fp32 -> bf16 RNE
    uint32_t u = __builtin_bit_cast(uint32_t, f);
    u += 0x7FFFu + ((u >> 16) & 1u);
    return (u16)(u >> 16);
}
__device__ __forceinline__ void g2l16(const void* g, void* l) {  // async global->LDS, 16B/lane
    __builtin_amdgcn_global_load_lds(
        (const __attribute__((address_space(1))) void*)g,
        (__attribute__((address_space(3))) void*)l, 16, 0, 0);
}

// ---------------- fused cast fp32 -> bf16 for all 5 tensors ----------------
__global__ void cast_all(const float* __restrict__ x, const float* __restrict__ wq,
                         const float* __restrict__ wk, const float* __restrict__ wv,
                         const float* __restrict__ wp,
                         u16* __restrict__ xb, u16* __restrict__ wqkvb, u16* __restrict__ wpb) {
    int bx = blockIdx.x;
    const float* src; u16* dst; int base;
    if (bx < 4096)      { src = x;  dst = xb;              base = bx; }
    else if (bx < 5120) { src = wq; dst = wqkvb;           base = bx - 4096; }
    else if (bx < 6144) { src = wk; dst = wqkvb + 1048576; base = bx - 5120; }
    else if (bx < 7168) { src = wv; dst = wqkvb + 2097152; base = bx - 6144; }
    else                { src = wp; dst = wpb;             base = bx - 7168; }
    int i = base * 1024 + threadIdx.x * 4;
    float4v v = *(const float4v*)(src + i);
    ushort4v o;
    #pragma unroll
    for (int r = 0; r < 4; ++r) o[r] = f2bf(v[r]);
    *(ushort4v*)(dst + i) = o;
}

// ---------------- shared NT-GEMM core: C[128x128] = A[128xK] * B[128xK]^T ----------------
// LDS tiles XOR-swizzled: logical 16B-chunk c of row r lives at physical chunk c^(r&7).
__device__ __forceinline__ void gemm_core_128(const u16* __restrict__ A, const u16* __restrict__ B,
                                              int K, int m0, int n0,
                                              u16* lA, u16* lB, float4v acc[4][4]) {
    const int tid = threadIdx.x, lane = tid & 63;
    const int wave = tid >> 6, wm = wave >> 1, wn = wave & 1;
    const int l15 = lane & 15, quad = lane >> 4;
    const int sw7 = l15 & 7;

    for (int kt = 0; kt < K; kt += 64) {
        __syncthreads();
        #pragma unroll
        for (int i = 0; i < 4; ++i) {   // stage 128x64 bf16 tiles, 16B/lane chunks, swizzled
            int f = i * 256 + tid;
            int row = f >> 3, kc = f & 7;
            int gcol = (kc ^ (row & 7)) * 8;
            g2l16(A + (size_t)(m0 + row) * K + kt + gcol, &lA[f * 8]);
            g2l16(B + (size_t)(n0 + row) * K + kt + gcol, &lB[f * 8]);
        }
        __syncthreads();
        #pragma unroll
        for (int ks = 0; ks < 2; ++ks) {
            short8 af[4], bf[4];
            #pragma unroll
            for (int t = 0; t < 4; ++t) {
                int pc = ((ks * 4 + quad) ^ sw7) * 8;   // physical chunk of logical col
                af[t] = *(const short8*)&lA[(wm * 64 + t * 16 + l15) * 64 + pc];
                bf[t] = *(const short8*)&lB[(wn * 64 + t * 16 + l15) * 64 + pc];
            }
            #pragma unroll
            for (int tm = 0; tm < 4; ++tm)
                #pragma unroll
                for (int tn = 0; tn < 4; ++tn)
                    acc[tm][tn] = MFMA_BF16(af[tm], bf[tn], acc[tm][tn]);
        }
    }
}

// ---------------- GEMM1: QKV projections ----------------
// q/k blocks (bx<16): transposed compute C[feat][t]; epilogue bounces through LDS so global
// stores are 16B/lane over contiguous 1KB spans. v blocks: C[t][n] -> v^T layout.
__global__ __launch_bounds__(256, 2) void gemm_qkv(
    const u16* __restrict__ xb, const u16* __restrict__ wqkv,
    const float* __restrict__ bq, const float* __restrict__ bk, const float* __restrict__ bv,
    u16* __restrict__ qo, u16* __restrict__ ko, u16* __restrict__ vto) {
    __shared__ __attribute__((aligned(16))) u16 ls[16384];   // 32 KB: staging + bounce reuse
    const int bx = blockIdx.x, by = blockIdx.y;
    const int tid = threadIdx.x, lane = tid & 63;
    const int wave = tid >> 6, wm = wave >> 1, wn = wave & 1;
    const int l15 = lane & 15, quad = lane >> 4;
    const float QSC = 0.125f * 1.44269504088896340736f;  // softmax scale * log2(e) folded into q

    if (bx < 16) {
        float4v acc[4][4] = {};
        gemm_core_128(wqkv, xb, 1024, bx * 128, by * 128, ls, ls + 8192, acc);  // C[feat][t]
        const bool isq = bx < 8;
        const float* bvec = isq ? bq : bk;
        u16* dst = isq ? qo : ko;
        const int b = by >> 4;
        #pragma unroll
        for (int h = 0; h < 2; ++h) {     // head-local = wm of producing waves
            __syncthreads();              // ls free (prior reads done)
            if (wm == h) {                // 2 waves own this head's acc rows
                #pragma unroll
                for (int tm = 0; tm < 4; ++tm) {
                    int fl = tm * 16 + quad * 4;                        // d 0..63 (4 consec)
                    int nloc = (bx & 7) * 128 + h * 64 + fl;
                    float4v bias = *(const float4v*)(bvec + nloc);
                    #pragma unroll
                    for (int tn = 0; tn < 4; ++tn) {
                        int t = wn * 64 + tn * 16 + l15;
                        ushort4v pk;
                        #pragma unroll
                        for (int r = 0; r < 4; ++r) {
                            float v = acc[tm][tn][r] + bias[r];
                            pk[r] = f2bf(isq ? v * QSC : v);
                        }
                        *(ushort4v*)&ls[t * 72 + fl] = pk;   // [t][d+8pad], stride 72 u16
                    }
                }
            }
            __syncthreads();
            int hg = (bx & 7) * 2 + h;                 // global head
            int c8 = (tid & 7) * 8, tr = tid >> 3;     // d0, t-row within round
            #pragma unroll
            for (int rnd = 0; rnd < 4; ++rnd) {        // 4 x (32 t-rows x 64 d) = 128x64
                int t = rnd * 32 + tr;
                uint4v v = *(const uint4v*)&ls[t * 72 + c8];
                int tg = (by * 128 + t) & 2047;
                *(uint4v*)&dst[(((size_t)(b * 16 + hg)) * 2048 + tg) * 64 + c8] = v;
            }
        }
    } else {
        float4v acc[4][4] = {};
        gemm_core_128(xb, wqkv, 1024, by * 128, bx * 128, ls, ls + 8192, acc);  // C[t][n]
        #pragma unroll
        for (int tn = 0; tn < 4; ++tn) {
            int n = bx * 128 + wn * 64 + tn * 16 + l15;
            int cb = n & 1023, h = cb >> 6, d = cb & 63;
            float bias = bv[cb];
            #pragma unroll
            for (int tm = 0; tm < 4; ++tm) {
                int mb = by * 128 + wm * 64 + tm * 16 + quad * 4;
                int b = mb >> 11, t0 = mb & 2047;
                ushort4v pk;
                #pragma unroll
                for (int r = 0; r < 4; ++r) pk[r] = f2bf(acc[tm][tn][r] + bias);
                *(ushort4v*)&vto[(((size_t)(b * 16 + h)) * 64 + d) * 2048 + t0] = pk;
            }
        }
    }
}

// ---------------- GEMM2: C[t][n] -> scalar stores fill 4 full 64B segments/instr ----------
__global__ __launch_bounds__(256, 2) void gemm_out(
    const u16* __restrict__ yb, const u16* __restrict__ wpb,
    const float* __restrict__ bp, float* __restrict__ out) {
    __shared__ __attribute__((aligned(16))) u16 ls[16384];
    float4v acc[4][4] = {};
    gemm_core_128(yb, wpb, 1024, blockIdx.y * 128, blockIdx.x * 128, ls, ls + 8192, acc);
    const int tid = threadIdx.x, lane = tid & 63;
    const int wave = tid >> 6, wm = wave >> 1, wn = wave & 1;
    const int l15 = lane & 15, quad = lane >> 4;
    #pragma unroll
    for (int tn = 0; tn < 4; ++tn) {
        int n = blockIdx.x * 128 + wn * 64 + tn * 16 + l15;
        float bias = bp[n];
        #pragma unroll
        for (int tm = 0; tm < 4; ++tm) {
            #pragma unroll
            for (int r = 0; r < 4; ++r) {
                int m = blockIdx.y * 128 + wm * 64 + tm * 16 + quad * 4 + r;
                out[(size_t)m * 1024 + n] = acc[tm][tn][r] + bias;
            }
        }
    }
}

// ---------------- flash attention v3 ----------------
// Per round-4 structure, plus: (1) softmax denominators via ones-row MFMA on the SAME
// truncated-P fragments (numerator/denominator consistent, zero rowsum VALU, no shuffles);
// (2) V^T fragment loads issued at iter top so VMEM latency hides under the S-phase.
__global__ __launch_bounds__(256, 2) void attn(
    const u16* __restrict__ qg, const u16* __restrict__ kg,
    const u16* __restrict__ vtg, u16* __restrict__ yb) {
    __shared__ __attribute__((aligned(16))) char smem[54272];
    u16* kb0 = (u16*)smem;                    // 2 x 128x64 u16 = 32768 B (XOR-swizzled)
    u16* pb  = (u16*)(smem + 32768);          // 4 waves x 64q x 40(32 kv + 8 pad) = 20480 B
    float* lsum = (float*)(smem + 53248);     // 4 x 64 = 1024 B
    float* red  = (float*)smem;               // reduction scratch (reused, 49152 B)

    const int tid = threadIdx.x, lane = tid & 63;
    const int w = tid >> 6;
    const int l15 = lane & 15, quad = lane >> 4, sw7 = l15 & 7;
    const int bh = blockIdx.y, qt0 = blockIdx.x * 64;

    const u16* qbase = qg + (size_t)bh * 2048 * 64;
    const u16* kbase = kg + (size_t)bh * 2048 * 64;
    const u16* vtbase = vtg + (size_t)bh * 64 * 2048;
    u16* pw = pb + w * 2560;                  // this wave's private P buffer [64][40]

    short8 ones;                              // bf16 1.0 frag for the denominator MFMA
    #pragma unroll
    for (int j = 0; j < 8; ++j) ones[j] = (short)0x3F80;

    short8 qf[4][2];  // q rows (B-operand), persistent
    #pragma unroll
    for (int tn = 0; tn < 4; ++tn)
        #pragma unroll
        for (int ks = 0; ks < 2; ++ks)
            qf[tn][ks] = *(const short8*)(qbase + (size_t)(qt0 + tn * 16 + l15) * 64 + ks * 32 + quad * 8);

    float4v oacc[4][4] = {};  // O^T[d 64][q 64] over this wave's kv-quarter
    float4v osum[4] = {};     // denominator accumulators (all rows identical)

    // prologue: DMA tile 0 -> buffer 0 (swizzled)
    #pragma unroll
    for (int i = 0; i < 4; ++i) {
        int f = i * 256 + tid, row = f >> 3, kc = f & 7;
        g2l16(kbase + (size_t)row * 64 + (kc ^ (row & 7)) * 8, &kb0[f * 8]);
    }

    for (int it = 0; it < 16; ++it) {
        __syncthreads();  // drains DMA(it) [issued one compute-phase ago]; syncs kb reuse
        if (it + 1 < 16) {  // issue DMA(it+1); completes during this iter's compute
            u16* nb = kb0 + ((it + 1) & 1) * 8192;
            const u16* src = kbase + (size_t)(it + 1) * 128 * 64;
            #pragma unroll
            for (int i = 0; i < 4; ++i) {
                int f = i * 256 + tid, row = f >> 3, kc = f & 7;
                g2l16(src + (size_t)row * 64 + (kc ^ (row & 7)) * 8, &nb[f * 8]);
            }
        }
        short8 vf[4];     // V^T frags: issue now, consumed after S-phase (latency hidden)
        #pragma unroll
        for (int tmm = 0; tmm < 4; ++tmm)
            vf[tmm] = *(const short8*)(vtbase + (size_t)(tmm * 16 + l15) * 2048 + it * 128 + w * 32 + quad * 8);
        const u16* kbu = kb0 + (it & 1) * 8192;
        // S^T = K @ Q^T : this wave's kv rows w*32..+31, all 64 q, K=64 (d)
        float4v sacc[2][4] = {};
        #pragma unroll
        for (int ks = 0; ks < 2; ++ks) {
            short8 kf[2];
            #pragma unroll
            for (int tm = 0; tm < 2; ++tm)
                kf[tm] = *(const short8*)&kbu[(w * 32 + tm * 16 + l15) * 64 + (((ks * 4 + quad) ^ sw7)) * 8];
            #pragma unroll
            for (int tm = 0; tm < 2; ++tm)
                #pragma unroll
                for (int tn = 0; tn < 4; ++tn)
                    sacc[tm][tn] = MFMA_BF16(kf[tm], qf[tn][ks], sacc[tm][tn]);
        }
        // P = exp2(S^T); truncate to bf16 (perm pack); packed b64 writes into pw[q][kv_local]
        #pragma unroll
        for (int tm = 0; tm < 2; ++tm)
            #pragma unroll
            for (int tn = 0; tn < 4; ++tn) {
                uint32_t u[4];
                #pragma unroll
                for (int r = 0; r < 4; ++r)
                    u[r] = __builtin_bit_cast(uint32_t, __builtin_amdgcn_exp2f(sacc[tm][tn][r]));
                uint2v pk;
                pk.x = __builtin_amdgcn_perm(u[1], u[0], 0x07060302u);
                pk.y = __builtin_amdgcn_perm(u[3], u[2], 0x07060302u);
                *(uint2v*)&pw[(tn * 16 + l15) * 40 + tm * 16 + quad * 4] = pk;
            }
        // O^T += V^T @ P^T over K=32; denominator row via ones-MFMA on same P frags
        short8 bfn[4];
        #pragma unroll
        for (int tnn = 0; tnn < 4; ++tnn)
            bfn[tnn] = *(const short8*)&pw[(tnn * 16 + l15) * 40 + quad * 8];
        #pragma unroll
        for (int tmm = 0; tmm < 4; ++tmm)
            #pragma unroll
            for (int tnn = 0; tnn < 4; ++tnn)
                oacc[tmm][tnn] = MFMA_BF16(vf[tmm], bfn[tnn], oacc[tmm][tnn]);
        #pragma unroll
        for (int tnn = 0; tnn < 4; ++tnn)
            osum[tnn] = MFMA_BF16(ones, bfn[tnn], osum[tnn]);
    }
    // publish per-wave denominators (every row of osum identical; quad 0 lanes write)
    if (lane < 16)
        #pragma unroll
        for (int tn = 0; tn < 4; ++tn)
            lsum[w * 64 + tn * 16 + l15] = osum[tn][0];
    __syncthreads();   // all loop LDS reads done; lsum visible; safe to reuse smem
    if (w > 0) {
        float* dst = red + (w - 1) * 4096;
        #pragma unroll
        for (int tmm = 0; tmm < 4; ++tmm)
            #pragma unroll
            for (int tnn = 0; tnn < 4; ++tnn)
                *(float4v*)&dst[((tmm * 4 + tnn) * 64 + lane) * 4] = oacc[tmm][tnn];
    }
    __syncthreads();
    if (w == 0) {
        const int b = bh >> 4, h = bh & 15;
        #pragma unroll
        for (int tmm = 0; tmm < 4; ++tmm)
            #pragma unroll
            for (int tnn = 0; tnn < 4; ++tnn) {
                float4v s = oacc[tmm][tnn];
                #pragma unroll
                for (int ww = 0; ww < 3; ++ww) {
                    float4v o = *(const float4v*)&red[(ww * 4096) + ((tmm * 4 + tnn) * 64 + lane) * 4];
                    #pragma unroll
                    for (int r = 0; r < 4; ++r) s[r] += o[r];
                }
                oacc[tmm][tnn] = s;
            }
        #pragma unroll
        for (int tnn = 0; tnn < 4; ++tnn) {
            int q = tnn * 16 + l15;
            float inv = 1.0f / (lsum[q] + lsum[64 + q] + lsum[128 + q] + lsum[192 + q]);
            #pragma unroll
            for (int tmm = 0; tmm < 4; ++tmm) {
                int d0 = tmm * 16 + quad * 4;
                ushort4v pk;
                #pragma unroll
                for (int r = 0; r < 4; ++r) pk[r] = f2bf(oacc[tmm][tnn][r] * inv);
                *(ushort4v*)&yb[((size_t)(b * 2048 + qt0 + q)) * 1024 + h * 64 + d0] = pk;
            }
        }
    }
}

extern "C" void kernel_launch(void* const* d_in, const int* in_sizes, int n_in,
                              void* d_out, int out_size, void* d_ws, size_t ws_size,
                              hipStream_t stream) {
    const float* x  = (const float*)d_in[0];
    const float* Wq = (const float*)d_in[1];
    const float* bq = (const float*)d_in[2];
    const float* Wk = (const float*)d_in[3];
    const float* bk = (const float*)d_in[4];
    const float* Wv = (const float*)d_in[5];
    const float* bv = (const float*)d_in[6];
    const float* Wp = (const float*)d_in[7];
    const float* bp = (const float*)d_in[8];
    float* out = (float*)d_out;
    uint8_t* ws = (uint8_t*)d_ws;

    u16* xb   = (u16*)(ws);                    // 8 MB  x bf16 [4096][1024]
    u16* wqkv = (u16*)(ws + (8u << 20));       // 6 MB  [Wq;Wk;Wv] bf16 [3072][1024]
    u16* wpb  = (u16*)(ws + (14u << 20));      // 2 MB  Wp bf16
    u16* qb   = (u16*)(ws + (16u << 20));      // 8 MB  q bf16 [32][2048][64] (pre-scaled)
    u16* kb   = (u16*)(ws + (24u << 20));      // 8 MB  k bf16 [32][2048][64]
    u16* vtb  = (u16*)(ws + (32u << 20));      // 8 MB  v^T bf16 [32][64][2048]
    u16* yb   = (u16*)(ws + (40u << 20));      // 8 MB  attn out bf16 [4096][1024]

    cast_all<<<8192, 256, 0, stream>>>(x, Wq, Wk, Wv, Wp, xb, wqkv, wpb);
    gemm_qkv<<<dim3(24, 32), 256, 0, stream>>>(xb, wqkv, bq, bk, bv, qb, kb, vtb);
    attn<<<dim3(32, 32), 256, 0, stream>>>(qb, kb, vtb, yb);
    gemm_out<<<dim3(8, 32), 256, 0, stream>>>(yb, wpb, bp, out);
}

// Round 6
// 197.297 us; speedup vs baseline: 1.0405x; 1.0405x over previous
//
#include <hip/hip_runtime.h>
#include <stdint.h>

typedef unsigned short u16;
typedef __attribute__((ext_vector_type(8))) short short8;    // 8 bf16 = 4 VGPRs (MFMA A/B frag)
typedef __attribute__((ext_vector_type(4))) float float4v;   // MFMA C/D frag
typedef __attribute__((ext_vector_type(4))) u16 ushort4v;
typedef __attribute__((ext_vector_type(4))) unsigned int uint4v;
typedef __attribute__((ext_vector_type(2))) unsigned int uint2v;

#define MFMA_BF16(a, b, c) __builtin_amdgcn_mfma_f32_16x16x32_bf16((a), (b), (c), 0, 0, 0)

__device__ __forceinline__ u16 f2bf(float f) {   // fp32 -> bf16 RNE
    uint32_t u = __builtin_bit_cast(uint32_t, f);
    u += 0x7FFFu + ((u >> 16) & 1u);
    return (u16)(u >> 16);
}
__device__ __forceinline__ void g2l16(const void* g, void* l) {  // async global->LDS, 16B/lane
    __builtin_amdgcn_global_load_lds(
        (const __attribute__((address_space(1))) void*)g,
        (__attribute__((address_space(3))) void*)l, 16, 0, 0);
}

// ---------------- fused cast fp32 -> bf16 for all 5 tensors ----------------
__global__ void cast_all(const float* __restrict__ x, const float* __restrict__ wq,
                         const float* __restrict__ wk, const float* __restrict__ wv,
                         const float* __restrict__ wp,
                         u16* __restrict__ xb, u16* __restrict__ wqkvb, u16* __restrict__ wpb) {
    int bx = blockIdx.x;
    const float* src; u16* dst; int base;
    if (bx < 4096)      { src = x;  dst = xb;              base = bx; }
    else if (bx < 5120) { src = wq; dst = wqkvb;           base = bx - 4096; }
    else if (bx < 6144) { src = wk; dst = wqkvb + 1048576; base = bx - 5120; }
    else if (bx < 7168) { src = wv; dst = wqkvb + 2097152; base = bx - 6144; }
    else                { src = wp; dst = wpb;             base = bx - 7168; }
    int i = base * 1024 + threadIdx.x * 4;
    float4v v = *(const float4v*)(src + i);
    ushort4v o;
    #pragma unroll
    for (int r = 0; r < 4; ++r) o[r] = f2bf(v[r]);
    *(ushort4v*)(dst + i) = o;
}

// ---------------- shared NT-GEMM core: C[128x128] = A[128xK] * B[128xK]^T ----------------
// LDS tiles XOR-swizzled: logical 16B-chunk c of row r lives at physical chunk c^(r&7).
__device__ __forceinline__ void gemm_core_128(const u16* __restrict__ A, const u16* __restrict__ B,
                                              int K, int m0, int n0,
                                              u16* lA, u16* lB, float4v acc[4][4]) {
    const int tid = threadIdx.x, lane = tid & 63;
    const int wave = tid >> 6, wm = wave >> 1, wn = wave & 1;
    const int l15 = lane & 15, quad = lane >> 4;
    const int sw7 = l15 & 7;

    for (int kt = 0; kt < K; kt += 64) {
        __syncthreads();
        #pragma unroll
        for (int i = 0; i < 4; ++i) {   // stage 128x64 bf16 tiles, 16B/lane chunks, swizzled
            int f = i * 256 + tid;
            int row = f >> 3, kc = f & 7;
            int gcol = (kc ^ (row & 7)) * 8;
            g2l16(A + (size_t)(m0 + row) * K + kt + gcol, &lA[f * 8]);
            g2l16(B + (size_t)(n0 + row) * K + kt + gcol, &lB[f * 8]);
        }
        __syncthreads();
        #pragma unroll
        for (int ks = 0; ks < 2; ++ks) {
            short8 af[4], bf[4];
            #pragma unroll
            for (int t = 0; t < 4; ++t) {
                int pc = ((ks * 4 + quad) ^ sw7) * 8;   // physical chunk of logical col
                af[t] = *(const short8*)&lA[(wm * 64 + t * 16 + l15) * 64 + pc];
                bf[t] = *(const short8*)&lB[(wn * 64 + t * 16 + l15) * 64 + pc];
            }
            #pragma unroll
            for (int tm = 0; tm < 4; ++tm)
                #pragma unroll
                for (int tn = 0; tn < 4; ++tn)
                    acc[tm][tn] = MFMA_BF16(af[tm], bf[tn], acc[tm][tn]);
        }
    }
}

// ---------------- GEMM1: QKV projections ----------------
// q/k blocks (bx<16): transposed compute C[feat][t]; epilogue bounces through LDS so global
// stores are 16B/lane over contiguous 1KB spans. v blocks: C[t][n] -> v^T layout.
__global__ __launch_bounds__(256, 2) void gemm_qkv(
    const u16* __restrict__ xb, const u16* __restrict__ wqkv,
    const float* __restrict__ bq, const float* __restrict__ bk, const float* __restrict__ bv,
    u16* __restrict__ qo, u16* __restrict__ ko, u16* __restrict__ vto) {
    __shared__ __attribute__((aligned(16))) u16 ls[16384];   // 32 KB: staging + bounce reuse
    const int bx = blockIdx.x, by = blockIdx.y;
    const int tid = threadIdx.x, lane = tid & 63;
    const int wave = tid >> 6, wm = wave >> 1, wn = wave & 1;
    const int l15 = lane & 15, quad = lane >> 4;
    const float QSC = 0.125f * 1.44269504088896340736f;  // softmax scale * log2(e) folded into q

    if (bx < 16) {
        float4v acc[4][4] = {};
        gemm_core_128(wqkv, xb, 1024, bx * 128, by * 128, ls, ls + 8192, acc);  // C[feat][t]
        const bool isq = bx < 8;
        const float* bvec = isq ? bq : bk;
        u16* dst = isq ? qo : ko;
        const int b = by >> 4;
        #pragma unroll
        for (int h = 0; h < 2; ++h) {     // head-local = wm of producing waves
            __syncthreads();              // ls free (prior reads done)
            if (wm == h) {                // 2 waves own this head's acc rows
                #pragma unroll
                for (int tm = 0; tm < 4; ++tm) {
                    int fl = tm * 16 + quad * 4;                        // d 0..63 (4 consec)
                    int nloc = (bx & 7) * 128 + h * 64 + fl;
                    float4v bias = *(const float4v*)(bvec + nloc);
                    #pragma unroll
                    for (int tn = 0; tn < 4; ++tn) {
                        int t = wn * 64 + tn * 16 + l15;
                        ushort4v pk;
                        #pragma unroll
                        for (int r = 0; r < 4; ++r) {
                            float v = acc[tm][tn][r] + bias[r];
                            pk[r] = f2bf(isq ? v * QSC : v);
                        }
                        *(ushort4v*)&ls[t * 72 + fl] = pk;   // [t][d+8pad], stride 72 u16
                    }
                }
            }
            __syncthreads();
            int hg = (bx & 7) * 2 + h;                 // global head
            int c8 = (tid & 7) * 8, tr = tid >> 3;     // d0, t-row within round
            #pragma unroll
            for (int rnd = 0; rnd < 4; ++rnd) {        // 4 x (32 t-rows x 64 d) = 128x64
                int t = rnd * 32 + tr;
                uint4v v = *(const uint4v*)&ls[t * 72 + c8];
                int tg = (by * 128 + t) & 2047;
                *(uint4v*)&dst[(((size_t)(b * 16 + hg)) * 2048 + tg) * 64 + c8] = v;
            }
        }
    } else {
        float4v acc[4][4] = {};
        gemm_core_128(xb, wqkv, 1024, by * 128, bx * 128, ls, ls + 8192, acc);  // C[t][n]
        #pragma unroll
        for (int tn = 0; tn < 4; ++tn) {
            int n = bx * 128 + wn * 64 + tn * 16 + l15;
            int cb = n & 1023, h = cb >> 6, d = cb & 63;
            float bias = bv[cb];
            #pragma unroll
            for (int tm = 0; tm < 4; ++tm) {
                int mb = by * 128 + wm * 64 + tm * 16 + quad * 4;
                int b = mb >> 11, t0 = mb & 2047;
                ushort4v pk;
                #pragma unroll
                for (int r = 0; r < 4; ++r) pk[r] = f2bf(acc[tm][tn][r] + bias);
                *(ushort4v*)&vto[(((size_t)(b * 16 + h)) * 64 + d) * 2048 + t0] = pk;
            }
        }
    }
}

// ---------------- GEMM2: C[t][n] -> scalar stores fill 4 full 64B segments/instr ----------
__global__ __launch_bounds__(256, 2) void gemm_out(
    const u16* __restrict__ yb, const u16* __restrict__ wpb,
    const float* __restrict__ bp, float* __restrict__ out) {
    __shared__ __attribute__((aligned(16))) u16 ls[16384];
    float4v acc[4][4] = {};
    gemm_core_128(yb, wpb, 1024, blockIdx.y * 128, blockIdx.x * 128, ls, ls + 8192, acc);
    const int tid = threadIdx.x, lane = tid & 63;
    const int wave = tid >> 6, wm = wave >> 1, wn = wave & 1;
    const int l15 = lane & 15, quad = lane >> 4;
    #pragma unroll
    for (int tn = 0; tn < 4; ++tn) {
        int n = blockIdx.x * 128 + wn * 64 + tn * 16 + l15;
        float bias = bp[n];
        #pragma unroll
        for (int tm = 0; tm < 4; ++tm) {
            #pragma unroll
            for (int r = 0; r < 4; ++r) {
                int m = blockIdx.y * 128 + wm * 64 + tm * 16 + quad * 4 + r;
                out[(size_t)m * 1024 + n] = acc[tm][tn][r] + bias;
            }
        }
    }
}

// ---------------- flash attention v4 ----------------
// Round-4 structure (measured 55.7 us) + one change: V^T fragments prefetched ONE ITERATION
// AHEAD. The top-of-iter __syncthreads drains vmcnt(0) anyway, so vf(it) issued during
// iter it-1 is guaranteed resident at the barrier -> the PV phase has zero mid-iteration
// vmem waits and never drains the in-flight DMA for tile it+1 (the round-5 regression).
__global__ __launch_bounds__(256, 2) void attn(
    const u16* __restrict__ qg, const u16* __restrict__ kg,
    const u16* __restrict__ vtg, u16* __restrict__ yb) {
    __shared__ __attribute__((aligned(16))) char smem[54272];
    u16* kb0 = (u16*)smem;                    // 2 x 128x64 u16 = 32768 B (XOR-swizzled)
    u16* pb  = (u16*)(smem + 32768);          // 4 waves x 64q x 40(32 kv + 8 pad) = 20480 B
    float* lsum = (float*)(smem + 53248);     // 4 x 64 = 1024 B
    float* red  = (float*)smem;               // reduction scratch (reused, 49152 B)

    const int tid = threadIdx.x, lane = tid & 63;
    const int w = tid >> 6;
    const int l15 = lane & 15, quad = lane >> 4, sw7 = l15 & 7;
    const int bh = blockIdx.y, qt0 = blockIdx.x * 64;

    const u16* qbase = qg + (size_t)bh * 2048 * 64;
    const u16* kbase = kg + (size_t)bh * 2048 * 64;
    const u16* vtbase = vtg + (size_t)bh * 64 * 2048;
    u16* pw = pb + w * 2560;                  // this wave's private P buffer [64][40]

    short8 qf[4][2];  // q rows (B-operand), persistent
    #pragma unroll
    for (int tn = 0; tn < 4; ++tn)
        #pragma unroll
        for (int ks = 0; ks < 2; ++ks)
            qf[tn][ks] = *(const short8*)(qbase + (size_t)(qt0 + tn * 16 + l15) * 64 + ks * 32 + quad * 8);

    float4v oacc[4][4] = {};  // O^T[d 64][q 64] over this wave's kv-quarter
    float rs[4] = {};

    short8 vfc[4], vfn[4];    // V^T frags: current / next (one-iter-ahead pipeline)
    #pragma unroll
    for (int tmm = 0; tmm < 4; ++tmm)
        vfc[tmm] = *(const short8*)(vtbase + (size_t)(tmm * 16 + l15) * 2048 + w * 32 + quad * 8);

    // prologue: DMA tile 0 -> buffer 0 (swizzled)
    #pragma unroll
    for (int i = 0; i < 4; ++i) {
        int f = i * 256 + tid, row = f >> 3, kc = f & 7;
        g2l16(kbase + (size_t)row * 64 + (kc ^ (row & 7)) * 8, &kb0[f * 8]);
    }

    for (int it = 0; it < 16; ++it) {
        __syncthreads();  // drains DMA(it) and vf(it) [both issued during iter it-1]
        if (it + 1 < 16) {  // issue DMA(it+1) + vf(it+1); both complete by next barrier
            u16* nb = kb0 + ((it + 1) & 1) * 8192;
            const u16* src = kbase + (size_t)(it + 1) * 128 * 64;
            #pragma unroll
            for (int i = 0; i < 4; ++i) {
                int f = i * 256 + tid, row = f >> 3, kc = f & 7;
                g2l16(src + (size_t)row * 64 + (kc ^ (row & 7)) * 8, &nb[f * 8]);
            }
            #pragma unroll
            for (int tmm = 0; tmm < 4; ++tmm)
                vfn[tmm] = *(const short8*)(vtbase + (size_t)(tmm * 16 + l15) * 2048 + (it + 1) * 128 + w * 32 + quad * 8);
        }
        const u16* kbu = kb0 + (it & 1) * 8192;
        // S^T = K @ Q^T : this wave's kv rows w*32..+31, all 64 q, K=64 (d)
        float4v sacc[2][4] = {};
        #pragma unroll
        for (int ks = 0; ks < 2; ++ks) {
            short8 kf[2];
            #pragma unroll
            for (int tm = 0; tm < 2; ++tm)
                kf[tm] = *(const short8*)&kbu[(w * 32 + tm * 16 + l15) * 64 + (((ks * 4 + quad) ^ sw7)) * 8];
            #pragma unroll
            for (int tm = 0; tm < 2; ++tm)
                #pragma unroll
                for (int tn = 0; tn < 4; ++tn)
                    sacc[tm][tn] = MFMA_BF16(kf[tm], qf[tn][ks], sacc[tm][tn]);
        }
        // P = exp2(S^T); truncate to bf16; packed b64 writes into per-wave pw[q][kv_local]
        #pragma unroll
        for (int tm = 0; tm < 2; ++tm)
            #pragma unroll
            for (int tn = 0; tn < 4; ++tn) {
                uint32_t u[4];
                #pragma unroll
                for (int r = 0; r < 4; ++r) {
                    float p = __builtin_amdgcn_exp2f(sacc[tm][tn][r]);
                    u[r] = __builtin_bit_cast(uint32_t, p);
                    rs[tn] += __builtin_bit_cast(float, u[r] & 0xFFFF0000u);
                }
                uint2v pk;
                pk.x = __builtin_amdgcn_perm(u[1], u[0], 0x07060302u);
                pk.y = __builtin_amdgcn_perm(u[3], u[2], 0x07060302u);
                *(uint2v*)&pw[(tn * 16 + l15) * 40 + tm * 16 + quad * 4] = pk;
            }
        // O^T += V^T @ P^T over K=32 (same-wave LDS RAW: in-order, no barrier)
        short8 bfn[4];
        #pragma unroll
        for (int tnn = 0; tnn < 4; ++tnn)
            bfn[tnn] = *(const short8*)&pw[(tnn * 16 + l15) * 40 + quad * 8];
        #pragma unroll
        for (int tmm = 0; tmm < 4; ++tmm)
            #pragma unroll
            for (int tnn = 0; tnn < 4; ++tnn)
                oacc[tmm][tnn] = MFMA_BF16(vfc[tmm], bfn[tnn], oacc[tmm][tnn]);
        if (it + 1 < 16) {
            #pragma unroll
            for (int tmm = 0; tmm < 4; ++tmm) vfc[tmm] = vfn[tmm];
        }
    }
    // per-wave softmax denominators: reduce across quads, publish
    #pragma unroll
    for (int tn = 0; tn < 4; ++tn) {
        float v = rs[tn];
        v += __shfl_xor(v, 16);
        v += __shfl_xor(v, 32);
        rs[tn] = v;
    }
    if (lane < 16)
        #pragma unroll
        for (int tn = 0; tn < 4; ++tn)
            lsum[w * 64 + tn * 16 + l15] = rs[tn];
    __syncthreads();   // all loop LDS reads done; lsum visible; safe to reuse smem
    if (w > 0) {
        float* dst = red + (w - 1) * 4096;
        #pragma unroll
        for (int tmm = 0; tmm < 4; ++tmm)
            #pragma unroll
            for (int tnn = 0; tnn < 4; ++tnn)
                *(float4v*)&dst[((tmm * 4 + tnn) * 64 + lane) * 4] = oacc[tmm][tnn];
    }
    __syncthreads();
    if (w == 0) {
        const int b = bh >> 4, h = bh & 15;
        #pragma unroll
        for (int tmm = 0; tmm < 4; ++tmm)
            #pragma unroll
            for (int tnn = 0; tnn < 4; ++tnn) {
                float4v s = oacc[tmm][tnn];
                #pragma unroll
                for (int ww = 0; ww < 3; ++ww) {
                    float4v o = *(const float4v*)&red[(ww * 4096) + ((tmm * 4 + tnn) * 64 + lane) * 4];
                    #pragma unroll
                    for (int r = 0; r < 4; ++r) s[r] += o[r];
                }
                oacc[tmm][tnn] = s;
            }
        #pragma unroll
        for (int tnn = 0; tnn < 4; ++tnn) {
            int q = tnn * 16 + l15;
            float inv = 1.0f / (lsum[q] + lsum[64 + q] + lsum[128 + q] + lsum[192 + q]);
            #pragma unroll
            for (int tmm = 0; tmm < 4; ++tmm) {
                int d0 = tmm * 16 + quad * 4;
                ushort4v pk;
                #pragma unroll
                for (int r = 0; r < 4; ++r) pk[r] = f2bf(oacc[tmm][tnn][r] * inv);
                *(ushort4v*)&yb[((size_t)(b * 2048 + qt0 + q)) * 1024 + h * 64 + d0] = pk;
            }
        }
    }
}

extern "C" void kernel_launch(void* const* d_in, const int* in_sizes, int n_in,
                              void* d_out, int out_size, void* d_ws, size_t ws_size,
                              hipStream_t stream) {
    const float* x  = (const float*)d_in[0];
    const float* Wq = (const float*)d_in[1];
    const float* bq = (const float*)d_in[2];
    const float* Wk = (const float*)d_in[3];
    const float* bk = (const float*)d_in[4];
    const float* Wv = (const float*)d_in[5];
    const float* bv = (const float*)d_in[6];
    const float* Wp = (const float*)d_in[7];
    const float* bp = (const float*)d_in[8];
    float* out = (float*)d_out;
    uint8_t* ws = (uint8_t*)d_ws;

    u16* xb   = (u16*)(ws);                    // 8 MB  x bf16 [4096][1024]
    u16* wqkv = (u16*)(ws + (8u << 20));       // 6 MB  [Wq;Wk;Wv] bf16 [3072][1024]
    u16* wpb  = (u16*)(ws + (14u << 20));      // 2 MB  Wp bf16
    u16* qb   = (u16*)(ws + (16u << 20));      // 8 MB  q bf16 [32][2048][64] (pre-scaled)
    u16* kb   = (u16*)(ws + (24u << 20));      // 8 MB  k bf16 [32][2048][64]
    u16* vtb  = (u16*)(ws + (32u << 20));      // 8 MB  v^T bf16 [32][64][2048]
    u16* yb   = (u16*)(ws + (40u << 20));      // 8 MB  attn out bf16 [4096][1024]

    cast_all<<<8192, 256, 0, stream>>>(x, Wq, Wk, Wv, Wp, xb, wqkv, wpb);
    gemm_qkv<<<dim3(24, 32), 256, 0, stream>>>(xb, wqkv, bq, bk, bv, qb, kb, vtb);
    attn<<<dim3(32, 32), 256, 0, stream>>>(qb, kb, vtb, yb);
    gemm_out<<<dim3(8, 32), 256, 0, stream>>>(yb, wpb, bp, out);
}

// Round 7
// 184.339 us; speedup vs baseline: 1.1136x; 1.0703x over previous
//
#include <hip/hip_runtime.h>
#include <stdint.h>

typedef unsigned short u16;
typedef __attribute__((ext_vector_type(8))) short short8;    // 8 bf16 = 4 VGPRs (MFMA A/B frag)
typedef __attribute__((ext_vector_type(4))) float float4v;   // MFMA C/D frag
typedef __attribute__((ext_vector_type(4))) u16 ushort4v;
typedef __attribute__((ext_vector_type(4))) unsigned int uint4v;
typedef __attribute__((ext_vector_type(2))) unsigned int uint2v;

#define MFMA_BF16(a, b, c) __builtin_amdgcn_mfma_f32_16x16x32_bf16((a), (b), (c), 0, 0, 0)

__device__ __forceinline__ u16 f2bf(float f) {   // fp32 -> bf16 RNE
    uint32_t u = __builtin_bit_cast(uint32_t, f);
    u += 0x7FFFu + ((u >> 16) & 1u);
    return (u16)(u >> 16);
}
__device__ __forceinline__ void g2l16(const void* g, void* l) {  // async global->LDS, 16B/lane
    __builtin_amdgcn_global_load_lds(
        (const __attribute__((address_space(1))) void*)g,
        (__attribute__((address_space(3))) void*)l, 16, 0, 0);
}

// ---------------- fused cast fp32 -> bf16 for all 5 tensors ----------------
__global__ void cast_all(const float* __restrict__ x, const float* __restrict__ wq,
                         const float* __restrict__ wk, const float* __restrict__ wv,
                         const float* __restrict__ wp,
                         u16* __restrict__ xb, u16* __restrict__ wqkvb, u16* __restrict__ wpb) {
    int bx = blockIdx.x;
    const float* src; u16* dst; int base;
    if (bx < 4096)      { src = x;  dst = xb;              base = bx; }
    else if (bx < 5120) { src = wq; dst = wqkvb;           base = bx - 4096; }
    else if (bx < 6144) { src = wk; dst = wqkvb + 1048576; base = bx - 5120; }
    else if (bx < 7168) { src = wv; dst = wqkvb + 2097152; base = bx - 6144; }
    else                { src = wp; dst = wpb;             base = bx - 7168; }
    int i = base * 1024 + threadIdx.x * 4;
    float4v v = *(const float4v*)(src + i);
    ushort4v o;
    #pragma unroll
    for (int r = 0; r < 4; ++r) o[r] = f2bf(v[r]);
    *(ushort4v*)(dst + i) = o;
}

// ---------------- shared NT-GEMM core: C[128x128] = A[128xK] * B[128xK]^T ----------------
// LDS tiles XOR-swizzled: logical 16B-chunk c of row r lives at physical chunk c^(r&7).
__device__ __forceinline__ void gemm_core_128(const u16* __restrict__ A, const u16* __restrict__ B,
                                              int K, int m0, int n0,
                                              u16* lA, u16* lB, float4v acc[4][4]) {
    const int tid = threadIdx.x, lane = tid & 63;
    const int wave = tid >> 6, wm = wave >> 1, wn = wave & 1;
    const int l15 = lane & 15, quad = lane >> 4;
    const int sw7 = l15 & 7;

    for (int kt = 0; kt < K; kt += 64) {
        __syncthreads();
        #pragma unroll
        for (int i = 0; i < 4; ++i) {   // stage 128x64 bf16 tiles, 16B/lane chunks, swizzled
            int f = i * 256 + tid;
            int row = f >> 3, kc = f & 7;
            int gcol = (kc ^ (row & 7)) * 8;
            g2l16(A + (size_t)(m0 + row) * K + kt + gcol, &lA[f * 8]);
            g2l16(B + (size_t)(n0 + row) * K + kt + gcol, &lB[f * 8]);
        }
        __syncthreads();
        #pragma unroll
        for (int ks = 0; ks < 2; ++ks) {
            short8 af[4], bf[4];
            #pragma unroll
            for (int t = 0; t < 4; ++t) {
                int pc = ((ks * 4 + quad) ^ sw7) * 8;   // physical chunk of logical col
                af[t] = *(const short8*)&lA[(wm * 64 + t * 16 + l15) * 64 + pc];
                bf[t] = *(const short8*)&lB[(wn * 64 + t * 16 + l15) * 64 + pc];
            }
            #pragma unroll
            for (int tm = 0; tm < 4; ++tm)
                #pragma unroll
                for (int tn = 0; tn < 4; ++tn)
                    acc[tm][tn] = MFMA_BF16(af[tm], bf[tn], acc[tm][tn]);
        }
    }
}

// ---------------- narrow NT-GEMM core: C[128x64] ----------------
__device__ __forceinline__ void gemm_core_128x64(const u16* __restrict__ A, const u16* __restrict__ B,
                                                 int K, int m0, int n0,
                                                 u16* lA, u16* lB, float4v acc[4][2]) {
    const int tid = threadIdx.x, lane = tid & 63;
    const int wave = tid >> 6, wm = wave >> 1, wn = wave & 1;
    const int l15 = lane & 15, quad = lane >> 4;
    const int sw7 = l15 & 7;

    for (int kt = 0; kt < K; kt += 64) {
        __syncthreads();
        #pragma unroll
        for (int i = 0; i < 4; ++i) {   // A tile 128x64
            int f = i * 256 + tid;
            int row = f >> 3, kc = f & 7;
            g2l16(A + (size_t)(m0 + row) * K + kt + (kc ^ (row & 7)) * 8, &lA[f * 8]);
        }
        #pragma unroll
        for (int i = 0; i < 2; ++i) {   // B tile 64x64
            int f = i * 256 + tid;
            int row = f >> 3, kc = f & 7;
            g2l16(B + (size_t)(n0 + row) * K + kt + (kc ^ (row & 7)) * 8, &lB[f * 8]);
        }
        __syncthreads();
        #pragma unroll
        for (int ks = 0; ks < 2; ++ks) {
            short8 af[4], bf[2];
            int pc = ((ks * 4 + quad) ^ sw7) * 8;
            #pragma unroll
            for (int t = 0; t < 4; ++t)
                af[t] = *(const short8*)&lA[(wm * 64 + t * 16 + l15) * 64 + pc];
            #pragma unroll
            for (int t = 0; t < 2; ++t)
                bf[t] = *(const short8*)&lB[(wn * 32 + t * 16 + l15) * 64 + pc];
            #pragma unroll
            for (int tm = 0; tm < 4; ++tm)
                #pragma unroll
                for (int tn = 0; tn < 2; ++tn)
                    acc[tm][tn] = MFMA_BF16(af[tm], bf[tn], acc[tm][tn]);
        }
    }
}

// ---------------- GEMM1: QKV projections ----------------
// q/k blocks (bx<16): transposed compute C[feat][t]; epilogue bounces through LDS so global
// stores are 16B/lane over contiguous 1KB spans. v blocks: C[t][n] -> v^T layout.
// launch_bounds(256,3): VGPR<=170 -> 3 blocks/CU (m97-equivalent occupancy), 768 blocks = 3/CU.
__global__ __launch_bounds__(256, 3) void gemm_qkv(
    const u16* __restrict__ xb, const u16* __restrict__ wqkv,
    const float* __restrict__ bq, const float* __restrict__ bk, const float* __restrict__ bv,
    u16* __restrict__ qo, u16* __restrict__ ko, u16* __restrict__ vto) {
    __shared__ __attribute__((aligned(16))) u16 ls[16384];   // 32 KB: staging + bounce reuse
    const int bx = blockIdx.x, by = blockIdx.y;
    const int tid = threadIdx.x, lane = tid & 63;
    const int wave = tid >> 6, wm = wave >> 1, wn = wave & 1;
    const int l15 = lane & 15, quad = lane >> 4;
    const float QSC = 0.125f * 1.44269504088896340736f;  // softmax scale * log2(e) folded into q

    if (bx < 16) {
        float4v acc[4][4] = {};
        gemm_core_128(wqkv, xb, 1024, bx * 128, by * 128, ls, ls + 8192, acc);  // C[feat][t]
        const bool isq = bx < 8;
        const float* bvec = isq ? bq : bk;
        u16* dst = isq ? qo : ko;
        const int b = by >> 4;
        #pragma unroll
        for (int h = 0; h < 2; ++h) {     // head-local = wm of producing waves
            __syncthreads();              // ls free (prior reads done)
            if (wm == h) {                // 2 waves own this head's acc rows
                #pragma unroll
                for (int tm = 0; tm < 4; ++tm) {
                    int fl = tm * 16 + quad * 4;                        // d 0..63 (4 consec)
                    int nloc = (bx & 7) * 128 + h * 64 + fl;
                    float4v bias = *(const float4v*)(bvec + nloc);
                    #pragma unroll
                    for (int tn = 0; tn < 4; ++tn) {
                        int t = wn * 64 + tn * 16 + l15;
                        ushort4v pk;
                        #pragma unroll
                        for (int r = 0; r < 4; ++r) {
                            float v = acc[tm][tn][r] + bias[r];
                            pk[r] = f2bf(isq ? v * QSC : v);
                        }
                        *(ushort4v*)&ls[t * 72 + fl] = pk;   // [t][d+8pad], stride 72 u16
                    }
                }
            }
            __syncthreads();
            int hg = (bx & 7) * 2 + h;                 // global head
            int c8 = (tid & 7) * 8, tr = tid >> 3;     // d0, t-row within round
            #pragma unroll
            for (int rnd = 0; rnd < 4; ++rnd) {        // 4 x (32 t-rows x 64 d) = 128x64
                int t = rnd * 32 + tr;
                uint4v v = *(const uint4v*)&ls[t * 72 + c8];
                int tg = (by * 128 + t) & 2047;
                *(uint4v*)&dst[(((size_t)(b * 16 + hg)) * 2048 + tg) * 64 + c8] = v;
            }
        }
    } else {
        float4v acc[4][4] = {};
        gemm_core_128(xb, wqkv, 1024, by * 128, bx * 128, ls, ls + 8192, acc);  // C[t][n]
        #pragma unroll
        for (int tn = 0; tn < 4; ++tn) {
            int n = bx * 128 + wn * 64 + tn * 16 + l15;
            int cb = n & 1023, h = cb >> 6, d = cb & 63;
            float bias = bv[cb];
            #pragma unroll
            for (int tm = 0; tm < 4; ++tm) {
                int mb = by * 128 + wm * 64 + tm * 16 + quad * 4;
                int b = mb >> 11, t0 = mb & 2047;
                ushort4v pk;
                #pragma unroll
                for (int r = 0; r < 4; ++r) pk[r] = f2bf(acc[tm][tn][r] + bias);
                *(ushort4v*)&vto[(((size_t)(b * 16 + h)) * 64 + d) * 2048 + t0] = pk;
            }
        }
    }
}

// ---------------- GEMM2: 128x64 tiles -> grid 512 = 2 blocks/CU uniform ----------------
__global__ __launch_bounds__(256, 3) void gemm_out(
    const u16* __restrict__ yb, const u16* __restrict__ wpb,
    const float* __restrict__ bp, float* __restrict__ out) {
    __shared__ __attribute__((aligned(16))) u16 ls[12288];   // lA 16 KB + lB 8 KB
    float4v acc[4][2] = {};
    gemm_core_128x64(yb, wpb, 1024, blockIdx.y * 128, blockIdx.x * 64, ls, ls + 8192, acc);
    const int tid = threadIdx.x, lane = tid & 63;
    const int wave = tid >> 6, wm = wave >> 1, wn = wave & 1;
    const int l15 = lane & 15, quad = lane >> 4;
    #pragma unroll
    for (int tn = 0; tn < 2; ++tn) {
        int n = blockIdx.x * 64 + wn * 32 + tn * 16 + l15;
        float bias = bp[n];
        #pragma unroll
        for (int tm = 0; tm < 4; ++tm) {
            #pragma unroll
            for (int r = 0; r < 4; ++r) {
                int m = blockIdx.y * 128 + wm * 64 + tm * 16 + quad * 4 + r;
                out[(size_t)m * 1024 + n] = acc[tm][tn][r] + bias;
            }
        }
    }
}

// ---------------- flash attention (round-4 measured-best structure, verbatim) ----------------
// S^T = K@Q^T per wave (32 kv x 64 q). P transpose via PER-WAVE LDS (no barrier).
// kbuf double-buffered: DMA for tile i+1 issued at top of iter i -> overlaps full compute phase.
// V^T frags loaded between P-write and PV (compiler schedules best here - measured r4 vs r5/r6).
__global__ __launch_bounds__(256, 2) void attn(
    const u16* __restrict__ qg, const u16* __restrict__ kg,
    const u16* __restrict__ vtg, u16* __restrict__ yb) {
    __shared__ __attribute__((aligned(16))) char smem[54272];
    u16* kb0 = (u16*)smem;                    // 2 x 128x64 u16 = 32768 B (XOR-swizzled)
    u16* pb  = (u16*)(smem + 32768);          // 4 waves x 64q x 40(32 kv + 8 pad) = 20480 B
    float* lsum = (float*)(smem + 53248);     // 4 x 64 = 1024 B
    float* red  = (float*)smem;               // reduction scratch (reused, 49152 B)

    const int tid = threadIdx.x, lane = tid & 63;
    const int w = tid >> 6;
    const int l15 = lane & 15, quad = lane >> 4, sw7 = l15 & 7;
    const int bh = blockIdx.y, qt0 = blockIdx.x * 64;

    const u16* qbase = qg + (size_t)bh * 2048 * 64;
    const u16* kbase = kg + (size_t)bh * 2048 * 64;
    const u16* vtbase = vtg + (size_t)bh * 64 * 2048;
    u16* pw = pb + w * 2560;                  // this wave's private P buffer [64][40]

    short8 qf[4][2];  // q rows (B-operand), persistent
    #pragma unroll
    for (int tn = 0; tn < 4; ++tn)
        #pragma unroll
        for (int ks = 0; ks < 2; ++ks)
            qf[tn][ks] = *(const short8*)(qbase + (size_t)(qt0 + tn * 16 + l15) * 64 + ks * 32 + quad * 8);

    float4v oacc[4][4] = {};  // O^T[d 64][q 64] over this wave's kv-quarter
    float rs[4] = {};

    // prologue: DMA tile 0 -> buffer 0 (swizzled)
    #pragma unroll
    for (int i = 0; i < 4; ++i) {
        int f = i * 256 + tid, row = f >> 3, kc = f & 7;
        g2l16(kbase + (size_t)row * 64 + (kc ^ (row & 7)) * 8, &kb0[f * 8]);
    }

    for (int it = 0; it < 16; ++it) {
        __syncthreads();  // drains DMA(it) [issued one compute-phase ago]; syncs kb reuse
        if (it + 1 < 16) {  // issue DMA(it+1); completes during this iter's compute
            u16* nb = kb0 + ((it + 1) & 1) * 8192;
            const u16* src = kbase + (size_t)(it + 1) * 128 * 64;
            #pragma unroll
            for (int i = 0; i < 4; ++i) {
                int f = i * 256 + tid, row = f >> 3, kc = f & 7;
                g2l16(src + (size_t)row * 64 + (kc ^ (row & 7)) * 8, &nb[f * 8]);
            }
        }
        const u16* kbu = kb0 + (it & 1) * 8192;
        // S^T = K @ Q^T : this wave's kv rows w*32..+31, all 64 q, K=64 (d)
        float4v sacc[2][4] = {};
        #pragma unroll
        for (int ks = 0; ks < 2; ++ks) {
            short8 kf[2];
            #pragma unroll
            for (int tm = 0; tm < 2; ++tm)
                kf[tm] = *(const short8*)&kbu[(w * 32 + tm * 16 + l15) * 64 + (((ks * 4 + quad) ^ sw7)) * 8];
            #pragma unroll
            for (int tm = 0; tm < 2; ++tm)
                #pragma unroll
                for (int tn = 0; tn < 4; ++tn)
                    sacc[tm][tn] = MFMA_BF16(kf[tm], qf[tn][ks], sacc[tm][tn]);
        }
        // P = exp2(S^T); truncate to bf16; packed b64 writes into per-wave pw[q][kv_local]
        #pragma unroll
        for (int tm = 0; tm < 2; ++tm)
            #pragma unroll
            for (int tn = 0; tn < 4; ++tn) {
                uint32_t u[4];
                #pragma unroll
                for (int r = 0; r < 4; ++r) {
                    float p = __builtin_amdgcn_exp2f(sacc[tm][tn][r]);
                    u[r] = __builtin_bit_cast(uint32_t, p);
                    rs[tn] += __builtin_bit_cast(float, u[r] & 0xFFFF0000u);
                }
                uint2v pk;
                pk.x = __builtin_amdgcn_perm(u[1], u[0], 0x07060302u);
                pk.y = __builtin_amdgcn_perm(u[3], u[2], 0x07060302u);
                *(uint2v*)&pw[(tn * 16 + l15) * 40 + tm * 16 + quad * 4] = pk;
            }
        // V^T frags for this wave's kv-quarter (global, L2/LLC-resident)
        short8 vf[4];
        #pragma unroll
        for (int tmm = 0; tmm < 4; ++tmm)
            vf[tmm] = *(const short8*)(vtbase + (size_t)(tmm * 16 + l15) * 2048 + it * 128 + w * 32 + quad * 8);
        // O^T += V^T @ P^T over K=32 (same-wave LDS RAW: in-order, no barrier)
        short8 bfn[4];
        #pragma unroll
        for (int tnn = 0; tnn < 4; ++tnn)
            bfn[tnn] = *(const short8*)&pw[(tnn * 16 + l15) * 40 + quad * 8];
        #pragma unroll
        for (int tmm = 0; tmm < 4; ++tmm)
            #pragma unroll
            for (int tnn = 0; tnn < 4; ++tnn)
                oacc[tmm][tnn] = MFMA_BF16(vf[tmm], bfn[tnn], oacc[tmm][tnn]);
    }
    // per-wave softmax denominators: reduce across quads, publish
    #pragma unroll
    for (int tn = 0; tn < 4; ++tn) {
        float v = rs[tn];
        v += __shfl_xor(v, 16);
        v += __shfl_xor(v, 32);
        rs[tn] = v;
    }
    if (lane < 16)
        #pragma unroll
        for (int tn = 0; tn < 4; ++tn)
            lsum[w * 64 + tn * 16 + l15] = rs[tn];
    __syncthreads();   // all loop LDS reads done; lsum visible; safe to reuse smem
    if (w > 0) {
        float* dst = red + (w - 1) * 4096;
        #pragma unroll
        for (int tmm = 0; tmm < 4; ++tmm)
            #pragma unroll
            for (int tnn = 0; tnn < 4; ++tnn)
                *(float4v*)&dst[((tmm * 4 + tnn) * 64 + lane) * 4] = oacc[tmm][tnn];
    }
    __syncthreads();
    if (w == 0) {
        const int b = bh >> 4, h = bh & 15;
        #pragma unroll
        for (int tmm = 0; tmm < 4; ++tmm)
            #pragma unroll
            for (int tnn = 0; tnn < 4; ++tnn) {
                float4v s = oacc[tmm][tnn];
                #pragma unroll
                for (int ww = 0; ww < 3; ++ww) {
                    float4v o = *(const float4v*)&red[(ww * 4096) + ((tmm * 4 + tnn) * 64 + lane) * 4];
                    #pragma unroll
                    for (int r = 0; r < 4; ++r) s[r] += o[r];
                }
                oacc[tmm][tnn] = s;
            }
        #pragma unroll
        for (int tnn = 0; tnn < 4; ++tnn) {
            int q = tnn * 16 + l15;
            float inv = 1.0f / (lsum[q] + lsum[64 + q] + lsum[128 + q] + lsum[192 + q]);
            #pragma unroll
            for (int tmm = 0; tmm < 4; ++tmm) {
                int d0 = tmm * 16 + quad * 4;
                ushort4v pk;
                #pragma unroll
                for (int r = 0; r < 4; ++r) pk[r] = f2bf(oacc[tmm][tnn][r] * inv);
                *(ushort4v*)&yb[((size_t)(b * 2048 + qt0 + q)) * 1024 + h * 64 + d0] = pk;
            }
        }
    }
}

extern "C" void kernel_launch(void* const* d_in, const int* in_sizes, int n_in,
                              void* d_out, int out_size, void* d_ws, size_t ws_size,
                              hipStream_t stream) {
    const float* x  = (const float*)d_in[0];
    const float* Wq = (const float*)d_in[1];
    const float* bq = (const float*)d_in[2];
    const float* Wk = (const float*)d_in[3];
    const float* bk = (const float*)d_in[4];
    const float* Wv = (const float*)d_in[5];
    const float* bv = (const float*)d_in[6];
    const float* Wp = (const float*)d_in[7];
    const float* bp = (const float*)d_in[8];
    float* out = (float*)d_out;
    uint8_t* ws = (uint8_t*)d_ws;

    u16* xb   = (u16*)(ws);                    // 8 MB  x bf16 [4096][1024]
    u16* wqkv = (u16*)(ws + (8u << 20));       // 6 MB  [Wq;Wk;Wv] bf16 [3072][1024]
    u16* wpb  = (u16*)(ws + (14u << 20));      // 2 MB  Wp bf16
    u16* qb   = (u16*)(ws + (16u << 20));      // 8 MB  q bf16 [32][2048][64] (pre-scaled)
    u16* kb   = (u16*)(ws + (24u << 20));      // 8 MB  k bf16 [32][2048][64]
    u16* vtb  = (u16*)(ws + (32u << 20));      // 8 MB  v^T bf16 [32][64][2048]
    u16* yb   = (u16*)(ws + (40u << 20));      // 8 MB  attn out bf16 [4096][1024]

    cast_all<<<8192, 256, 0, stream>>>(x, Wq, Wk, Wv, Wp, xb, wqkv, wpb);
    gemm_qkv<<<dim3(24, 32), 256, 0, stream>>>(xb, wqkv, bq, bk, bv, qb, kb, vtb);
    attn<<<dim3(32, 32), 256, 0, stream>>>(qb, kb, vtb, yb);
    gemm_out<<<dim3(16, 32), 256, 0, stream>>>(yb, wpb, bp, out);
}